// Round 5
// baseline (7945.171 us; speedup 1.0000x reference)
//
#include <hip/hip_runtime.h>
#include <hip/hip_bf16.h>

constexpr int B = 32, L = 1024, D = 512, H = 512;

// ---- LDS layout (dword offsets), all rows bank-swizzled ----
// WH: [3 gates][8 feats][512 k] f32                 = 12288 dw (48 KiB)
// XW: [3 gates][8 feats][256 k-pairs] u32 (2×bf16)  =  6144 dw (24 KiB)
// HB: [8 batch rows][512] f32 staged h              =  4096 dw (16 KiB)
// XB: 2 × [8 batch rows][512] f32 staged x (dbuf)   =  8192 dw (32 KiB)
constexpr int WH_OFF = 0;
constexpr int XW_OFF = 12288;
constexpr int HB_OFF = 18432;
constexpr int XB_OFF = 22528;
constexpr int LDS_DW = 30720;
constexpr size_t SMEM_BYTES = LDS_DW * 4ull;   // 122880 B (< 160 KiB cliff)

// ---- workspace layout (dword offsets) ----
constexpr int HGA_OFF = 0;          // h parity 0: [32][512] f32
constexpr int HGB_OFF = 16384;      // h parity 1
constexpr int FLAGS_OFF = 32768;    // [4 rings][64 members], stride 32 dw

using ull = unsigned long long;

__device__ __forceinline__ float dot4(float4 a, float4 b) {
    return a.x * b.x + a.y * b.y + a.z * b.z + a.w * b.w;
}
__device__ __forceinline__ float bflo(unsigned u) { return __uint_as_float(u << 16); }
__device__ __forceinline__ float bfhi(unsigned u) { return __uint_as_float(u & 0xffff0000u); }
__device__ __forceinline__ float bdot8(uint4 u, float4 lo, float4 hi) {
    return bflo(u.x)*lo.x + bfhi(u.x)*lo.y + bflo(u.y)*lo.z + bfhi(u.y)*lo.w
         + bflo(u.z)*hi.x + bfhi(u.z)*hi.y + bflo(u.w)*hi.z + bfhi(u.w)*hi.w;
}
// swizzled dword position of element k within a 512-dw row
__device__ __forceinline__ int swz(int k) {
    const int cg = k >> 2, e = k & 3, sup = cg >> 3;
    return sup * 32 + ((cg + sup) & 7) * 4 + e;
}
__device__ __forceinline__ int swzp(int p) {
    const int cg = p >> 2, e = p & 3, sup = cg >> 3;
    return sup * 32 + ((cg + sup) & 7) * 4 + e;
}
// sum over lane bits 0..3 (VALU pipe DPP)
__device__ __forceinline__ float red16(float v) {
    int i;
    i = __builtin_amdgcn_update_dpp(0, __float_as_int(v), 0xB1, 0xf, 0xf, true);
    v += __int_as_float(i);
    i = __builtin_amdgcn_update_dpp(0, __float_as_int(v), 0x4E, 0xf, 0xf, true);
    v += __int_as_float(i);
    i = __builtin_amdgcn_update_dpp(0, __float_as_int(v), 0x124, 0xf, 0xf, true);
    v += __int_as_float(i);
    i = __builtin_amdgcn_update_dpp(0, __float_as_int(v), 0x128, 0xf, 0xf, true);
    v += __int_as_float(i);
    return v;
}
__device__ __forceinline__ float redk(float v) {
    v = red16(v);
    return v + __shfl_xor(v, 32);
}

__global__ __launch_bounds__(256, 1)
void gru_ring(const float* __restrict__ x, const float* __restrict__ h0,
              const float* __restrict__ Wxz, const float* __restrict__ Whz,
              const float* __restrict__ bz,
              const float* __restrict__ Wxr, const float* __restrict__ Whr,
              const float* __restrict__ br,
              const float* __restrict__ Wxh, const float* __restrict__ Whh,
              const float* __restrict__ bh,
              float* __restrict__ out, unsigned* __restrict__ ws)
{
    extern __shared__ float lds[];
    float*    WHl = lds + WH_OFF;
    unsigned* XWl = (unsigned*)(lds + XW_OFF);
    float*    HBl = lds + HB_OFF;
    float*    XBl = lds + XB_OFF;

    const int tid = threadIdx.x;
    const int bid = blockIdx.x;
    // ring/member remap for XCD affinity: ring g = blocks with bid%4==g →
    // XCD residues {g, g+4} only, so the shared x-slice lives in ≤2 L2s.
    const int g   = bid & 3;         // ring: batches g*8 .. g*8+7
    const int fc  = bid >> 2;        // member: features fc*8 .. fc*8+7
    const int F0  = fc * 8;

    float*    hgA   = (float*)(ws + HGA_OFF);
    float*    hgB   = (float*)(ws + HGB_OFF);
    unsigned* flags = ws + FLAGS_OFF + g * 64 * 32;   // ring-local

    // ---------------- one-time weight staging ----------------
    for (int gi = 0; gi < 3; ++gi) {
        const float* Wh = gi == 0 ? Whz : gi == 1 ? Whr : Whh;
        const float* Wx = gi == 0 ? Wxz : gi == 1 ? Wxr : Wxh;
        for (int rep = 0; rep < 2; ++rep) {
            const int k = tid + rep * 256;
            const float* src = Wh + (size_t)k * H + F0;
            const float4 a = *(const float4*)(src);
            const float4 b = *(const float4*)(src + 4);
            const float va[8] = {a.x, a.y, a.z, a.w, b.x, b.y, b.z, b.w};
            const int dk = swz(k);
#pragma unroll
            for (int f = 0; f < 8; ++f)
                WHl[(gi * 8 + f) * 512 + dk] = va[f];
        }
        {
            const int p = tid;               // k-pair: rows 2p, 2p+1
            const float* s0 = Wx + (size_t)(2 * p) * H + F0;
            const float* s1 = Wx + (size_t)(2 * p + 1) * H + F0;
            const float4 a0 = *(const float4*)(s0), b0 = *(const float4*)(s0 + 4);
            const float4 a1 = *(const float4*)(s1), b1 = *(const float4*)(s1 + 4);
            const float v0[8] = {a0.x, a0.y, a0.z, a0.w, b0.x, b0.y, b0.z, b0.w};
            const float v1[8] = {a1.x, a1.y, a1.z, a1.w, b1.x, b1.y, b1.z, b1.w};
            const int dp = swzp(p);
#pragma unroll
            for (int f = 0; f < 8; ++f) {
                __hip_bfloat16 lo = __float2bfloat16(v0[f]);
                __hip_bfloat16 hi = __float2bfloat16(v1[f]);
                const unsigned u = ((unsigned)*(unsigned short*)&hi << 16) |
                                   (unsigned)*(unsigned short*)&lo;
                XWl[(gi * 8 + f) * 256 + dp] = u;
            }
        }
    }

    // ---- compute-role decomposition ----
    const int ks = (tid & 15) | ((tid & 32) >> 1);   // k-slice 0..31 (16 k each)
    const int bhalf = (tid >> 4) & 1;                // batches bhalf*4 .. +3
    const int f2 = tid >> 6;                         // feature pair 2f2, 2f2+1

    int oh[4];
    {
        const int sup = ks >> 1;
#pragma unroll
        for (int c = 0; c < 4; ++c)
            oh[c] = sup * 32 + (((4 * ks + c) + sup) & 7) * 4;
    }
    int ox2[2];
    {
        const int sup = ks >> 2;
#pragma unroll
        for (int cc = 0; cc < 2; ++cc)
            ox2[cc] = sup * 32 + (((2 * ks + cc) + sup) & 7) * 4;
    }

    const int f0g = F0 + 2 * f2;
    const float bz0 = bz[f0g], bz1 = bz[f0g + 1];
    const float br0 = br[f0g], br1 = br[f0g + 1];
    const float bhv0 = bh[f0g], bhv1 = bh[f0g + 1];

    // ---- staging roles: row rr (ring-local batch), 16 cols from cbase ----
    const int rr    = tid >> 5;
    const int cbase = (tid & 31) * 16;
    int os[4];
    {
        const int kss = tid & 31, sup = kss >> 1;
#pragma unroll
        for (int c = 0; c < 4; ++c)
            os[c] = sup * 32 + (((4 * kss + c) + sup) & 7) * 4;
    }

    // init h parity-0 with this block's own feature columns
    if (tid < 64) {
        const int bb = tid >> 3, j = tid & 7;
        const int idx = (g * 8 + bb) * H + F0 + j;
        __hip_atomic_store(&hgA[idx], h0[idx], __ATOMIC_RELAXED,
                           __HIP_MEMORY_SCOPE_AGENT);
    }

    // prologue: stage x(0) into XB parity-0, prefetch x(1) into regs
    float4 xr[4];
    {
        const float* xp = x + ((size_t)(g * 8 + rr) * L + 0) * D + cbase;
#pragma unroll
        for (int c = 0; c < 4; ++c) xr[c] = *(const float4*)(xp + 4 * c);
#pragma unroll
        for (int c = 0; c < 4; ++c)
            *(float4*)(XBl + rr * 512 + os[c]) = xr[c];
        const float* xq = x + ((size_t)(g * 8 + rr) * L + 1) * D + cbase;
#pragma unroll
        for (int c = 0; c < 4; ++c) xr[c] = *(const float4*)(xq + 4 * c);
    }

    asm volatile("s_waitcnt vmcnt(0)" ::: "memory");
    __syncthreads();
    if (tid == 0)
        __hip_atomic_store(&flags[fc * 32], 1u, __ATOMIC_RELAXED,
                           __HIP_MEMORY_SCOPE_AGENT);

    for (int t = 0; t < L; ++t) {
        // ---- G: x-dots for step t (no h dependency — runs while other
        //         members finish step t-1 and flags propagate) ----
        float pz[4][2] = {}, pr2[4][2] = {}, px[4][2] = {};
        {
            const unsigned* U0 = XWl + (0 * 8 + 2 * f2) * 256;
            const unsigned* U1 = XWl + (1 * 8 + 2 * f2) * 256;
            const unsigned* U2 = XWl + (2 * 8 + 2 * f2) * 256;
            const float* xb = XBl + (t & 1) * 4096 + (bhalf * 4) * 512;
#pragma unroll
            for (int cc = 0; cc < 2; ++cc) {
                const int o2 = ox2[cc];
                const uint4 uz0 = *(const uint4*)(U0 + o2);
                const uint4 uz1 = *(const uint4*)(U0 + 256 + o2);
                const uint4 ur0 = *(const uint4*)(U1 + o2);
                const uint4 ur1 = *(const uint4*)(U1 + 256 + o2);
                const uint4 uc0 = *(const uint4*)(U2 + o2);
                const uint4 uc1 = *(const uint4*)(U2 + 256 + o2);
#pragma unroll
                for (int b = 0; b < 4; ++b) {
                    const float4 xlo = *(const float4*)(xb + b * 512 + oh[2 * cc]);
                    const float4 xhi = *(const float4*)(xb + b * 512 + oh[2 * cc + 1]);
                    pz[b][0] += bdot8(uz0, xlo, xhi); pz[b][1] += bdot8(uz1, xlo, xhi);
                    pr2[b][0] += bdot8(ur0, xlo, xhi); pr2[b][1] += bdot8(ur1, xlo, xhi);
                    px[b][0] += bdot8(uc0, xlo, xhi); px[b][1] += bdot8(uc1, xlo, xhi);
                }
            }
        }

        // ---- A: ring barrier — all 64 members' flags in {t+1, t+2} ----
        const unsigned stamp = (unsigned)(t + 1);
        if (tid < 64) {
            unsigned v;
            do {
                v = __hip_atomic_load(&flags[tid * 32], __ATOMIC_RELAXED,
                                      __HIP_MEMORY_SCOPE_AGENT);
                if (__all((v - stamp) <= 1u)) break;
                __builtin_amdgcn_s_sleep(1);
            } while (true);
        }
        __syncthreads();

        // ---- C: stage h(t) into HB; stage x(t+1) regs into XB[(t+1)&1] ----
        {
            const float* hsrc = ((t & 1) ? hgB : hgA) + (g * 8 + rr) * 512 + cbase;
            const ull* hq = (const ull*)hsrc;
#pragma unroll
            for (int c = 0; c < 4; ++c) {
                const ull q0 = __hip_atomic_load(hq + 2 * c,     __ATOMIC_RELAXED, __HIP_MEMORY_SCOPE_AGENT);
                const ull q1 = __hip_atomic_load(hq + 2 * c + 1, __ATOMIC_RELAXED, __HIP_MEMORY_SCOPE_AGENT);
                float4 h4;
                h4.x = __uint_as_float((unsigned)q0);
                h4.y = __uint_as_float((unsigned)(q0 >> 32));
                h4.z = __uint_as_float((unsigned)q1);
                h4.w = __uint_as_float((unsigned)(q1 >> 32));
                *(float4*)(HBl + rr * 512 + os[c]) = h4;
            }
            if (t + 1 < L) {
                float* xbw = XBl + ((t + 1) & 1) * 4096;
#pragma unroll
                for (int c = 0; c < 4; ++c)
                    *(float4*)(xbw + rr * 512 + os[c]) = xr[c];
            }
        }
        __syncthreads();

        // ---- E: h-dots + combine with x partials ----
        float az[4][2] = {}, ar[4][2] = {}, ac[4][2] = {};
        {
            const float* W0 = WHl + (0 * 8 + 2 * f2) * 512;
            const float* W1 = WHl + (1 * 8 + 2 * f2) * 512;
            const float* W2 = WHl + (2 * 8 + 2 * f2) * 512;
            const float* hb = HBl + (bhalf * 4) * 512;
#pragma unroll
            for (int c = 0; c < 4; ++c) {
                const int o = oh[c];
                const float4 wz0 = *(const float4*)(W0 + o);
                const float4 wz1 = *(const float4*)(W0 + 512 + o);
                const float4 wr0 = *(const float4*)(W1 + o);
                const float4 wr1 = *(const float4*)(W1 + 512 + o);
                const float4 wc0 = *(const float4*)(W2 + o);
                const float4 wc1 = *(const float4*)(W2 + 512 + o);
#pragma unroll
                for (int b = 0; b < 4; ++b) {
                    const float4 h4 = *(const float4*)(hb + b * 512 + o);
                    az[b][0] += dot4(h4, wz0); az[b][1] += dot4(h4, wz1);
                    ar[b][0] += dot4(h4, wr0); ar[b][1] += dot4(h4, wr1);
                    ac[b][0] += dot4(h4, wc0); ac[b][1] += dot4(h4, wc1);
                }
            }
        }

        // ---- reduce over the 32 k-slices ----
#pragma unroll
        for (int b = 0; b < 4; ++b) {
#pragma unroll
            for (int j = 0; j < 2; ++j) {
                az[b][j] = redk(az[b][j] + pz[b][j]);
                ar[b][j] = redk(ar[b][j] + pr2[b][j]);
                ac[b][j] = redk(ac[b][j]);
                px[b][j] = redk(px[b][j]);
            }
        }

        // ---- F: epilogue on ks==0 threads ----
        float2 outv[4];
        const bool epi = (tid & 0x2F) == 0;
        if (epi) {
            float* hdst = ((t + 1) & 1) ? hgB : hgA;
            const int offh = swz(f0g);
#pragma unroll
            for (int b = 0; b < 4; ++b) {
                const int bb = bhalf * 4 + b;
                const int bg = g * 8 + bb;
                const float hold0 = HBl[bb * 512 + offh];
                const float hold1 = HBl[bb * 512 + offh + 1];

                const float z0 = 1.f / (1.f + __expf(-(az[b][0] + bz0)));
                const float r0 = 1.f / (1.f + __expf(-(ar[b][0] + br0)));
                const float p0 = px[b][0] + r0 * (ac[b][0] + bhv0);
                const float e0 = __expf(-2.f * fabsf(p0));
                float th0 = (1.f - e0) / (1.f + e0);
                th0 = (p0 < 0.f) ? -th0 : th0;
                const float hn0 = z0 * hold0 + (1.f - z0) * th0;

                const float z1 = 1.f / (1.f + __expf(-(az[b][1] + bz1)));
                const float r1 = 1.f / (1.f + __expf(-(ar[b][1] + br1)));
                const float p1 = px[b][1] + r1 * (ac[b][1] + bhv1);
                const float e1 = __expf(-2.f * fabsf(p1));
                float th1 = (1.f - e1) / (1.f + e1);
                th1 = (p1 < 0.f) ? -th1 : th1;
                const float hn1 = z1 * hold1 + (1.f - z1) * th1;

                const ull hp = ((ull)__float_as_uint(hn1) << 32) | __float_as_uint(hn0);
                __hip_atomic_store((ull*)(hdst + bg * 512 + f0g), hp,
                                   __ATOMIC_RELAXED, __HIP_MEMORY_SCOPE_AGENT);
                outv[b] = make_float2(hn0, hn1);
            }
        }

        // release h stores, arrive
        asm volatile("s_waitcnt vmcnt(0)" ::: "memory");
        __syncthreads();
        if (tid == 0)
            __hip_atomic_store(&flags[fc * 32], stamp + 1u, __ATOMIC_RELAXED,
                               __HIP_MEMORY_SCOPE_AGENT);

        // off the critical path: out writes + x prefetch for t+2
        if (epi) {
#pragma unroll
            for (int b = 0; b < 4; ++b) {
                const int bg = g * 8 + bhalf * 4 + b;
                *(float2*)(out + ((size_t)bg * L + t) * H + f0g) = outv[b];
                if (t == L - 1)
                    *(float2*)(out + (size_t)B * L * H + (size_t)bg * H + f0g) = outv[b];
            }
        }
        if (t + 2 < L) {
            const float* xp = x + ((size_t)(g * 8 + rr) * L + (t + 2)) * D + cbase;
#pragma unroll
            for (int c = 0; c < 4; ++c) xr[c] = *(const float4*)(xp + 4 * c);
        }
    }
}

extern "C" void kernel_launch(void* const* d_in, const int* in_sizes, int n_in,
                              void* d_out, int out_size, void* d_ws, size_t ws_size,
                              hipStream_t stream) {
    const float* x   = (const float*)d_in[0];
    const float* h0  = (const float*)d_in[1];
    const float* Wxz = (const float*)d_in[2];
    const float* Whz = (const float*)d_in[3];
    const float* bz  = (const float*)d_in[4];
    const float* Wxr = (const float*)d_in[5];
    const float* Whr = (const float*)d_in[6];
    const float* br  = (const float*)d_in[7];
    const float* Wxh = (const float*)d_in[8];
    const float* Whh = (const float*)d_in[9];
    const float* bh  = (const float*)d_in[10];
    float* out = (float*)d_out;
    unsigned* ws = (unsigned*)d_ws;

    (void)hipFuncSetAttribute((const void*)gru_ring,
                              hipFuncAttributeMaxDynamicSharedMemorySize,
                              (int)SMEM_BYTES);

    void* args[] = {(void*)&x, (void*)&h0, (void*)&Wxz, (void*)&Whz, (void*)&bz,
                    (void*)&Wxr, (void*)&Whr, (void*)&br, (void*)&Wxh, (void*)&Whh,
                    (void*)&bh, (void*)&out, (void*)&ws};
    hipError_t err = hipLaunchCooperativeKernel((void*)gru_ring, dim3(256),
                                                dim3(256), args,
                                                (unsigned)SMEM_BYTES, stream);
    if (err != hipSuccess) {
        // kernel uses only its own flag barrier; 256 blocks at 1/CU are
        // trivially co-resident, so a plain launch is a safe fallback
        gru_ring<<<dim3(256), dim3(256), SMEM_BYTES, stream>>>(
            x, h0, Wxz, Whz, bz, Wxr, Whr, br, Wxh, Whh, bh, out, ws);
    }
}

// Round 6
// 3634.992 us; speedup vs baseline: 2.1857x; 2.1857x over previous
//
#include <hip/hip_runtime.h>

constexpr int B = 32, L = 1024, D = 512, H = 512;

// ---- LDS byte offsets ----
// A operands: [16 rows][512 k] bf16, rows 8..15 permanently zero.
constexpr int AH_HI = 0;
constexpr int AH_LO = 16384;
constexpr int AX_HI = 32768;
constexpr int AX_LO = 49152;
// B operands: [2 tiles][16 n][512 k] bf16. BH tile0=[Whz|Whr] tile1=[Whh|0];
// BX tile0=[Wxz|Wxr] tile1=[0|Wxh].
constexpr int BH_OFF = 65536;
constexpr int BX_OFF = 98304;
// C partials: [4 waves][2 tiles][8 m][17] f32
constexpr int CB_OFF = 131072;
constexpr size_t SMEM_BYTES = 135424;   // 132.25 KiB < 160 KiB cliff

// ---- workspace dword offsets ----
constexpr int HGA_OFF = 0;          // h parity 0: [32][512] f32
constexpr int HGB_OFF = 16384;      // h parity 1
constexpr int FLAGS_OFF = 32768;    // [4 rings][64 members] stride 32 dw

typedef __attribute__((ext_vector_type(8))) short short8v;
typedef __attribute__((ext_vector_type(4))) float f32x4;
using ull = unsigned long long;

__device__ __forceinline__ unsigned short f2bf(float f) {   // RNE f32->bf16
    unsigned u = __float_as_uint(f);
    return (unsigned short)((u + 0x7FFFu + ((u >> 16) & 1u)) >> 16);
}
__device__ __forceinline__ float bf2f(unsigned short b) {
    return __uint_as_float((unsigned)b << 16);
}
// XOR-swizzled byte address of element-byte kbyte within a [row][1024B] tile
__device__ __forceinline__ int aswz(int row, int kbyte) {
    return row * 1024 + (kbyte ^ ((row & 7) << 4));
}
// 8 floats -> packed bf16 hi/lo uint4s (hi = bf16(v), lo = bf16(v - hi))
__device__ __forceinline__ void split8(const float* v, uint4& phi, uint4& plo) {
    unsigned hi[8], lo[8];
#pragma unroll
    for (int i = 0; i < 8; ++i) {
        const unsigned short h = f2bf(v[i]);
        hi[i] = h;
        lo[i] = f2bf(v[i] - bf2f(h));
    }
    phi = make_uint4(hi[0] | (hi[1] << 16), hi[2] | (hi[3] << 16),
                     hi[4] | (hi[5] << 16), hi[6] | (hi[7] << 16));
    plo = make_uint4(lo[0] | (lo[1] << 16), lo[2] | (lo[3] << 16),
                     lo[4] | (lo[5] << 16), lo[6] | (lo[7] << 16));
}

__global__ __launch_bounds__(256, 1)
void gru_mfma(const float* __restrict__ x, const float* __restrict__ h0,
              const float* __restrict__ Wxz, const float* __restrict__ Whz,
              const float* __restrict__ bz,
              const float* __restrict__ Wxr, const float* __restrict__ Whr,
              const float* __restrict__ br,
              const float* __restrict__ Wxh, const float* __restrict__ Whh,
              const float* __restrict__ bh,
              float* __restrict__ out, unsigned* __restrict__ ws)
{
    extern __shared__ char smem[];

    const int tid = threadIdx.x;
    const int bid = blockIdx.x;
    // XCD-affinity remap (R5, kept): ring g occupies XCD residues {g, g+4}
    const int g  = bid & 3;          // ring: batches g*8 .. g*8+7
    const int fc = bid >> 2;         // member: features fc*8 .. +7
    const int F0 = fc * 8;

    float*    hgA   = (float*)(ws + HGA_OFF);
    float*    hgB   = (float*)(ws + HGB_OFF);
    unsigned* flags = ws + FLAGS_OFF + g * 64 * 32;   // ring-local

    // ---- zero all LDS (A pad rows + B zero-blocks must stay zero) ----
    for (int i = tid; i < (int)(SMEM_BYTES / 16); i += 256)
        *(uint4*)(smem + i * 16) = make_uint4(0, 0, 0, 0);
    __syncthreads();

    // ---- one-time weight staging: bf16, swizzled [n][k] fragments ----
    {
        const float* WSET[2][3] = {{Whz, Whr, Whh}, {Wxz, Wxr, Wxh}};
        const int TB[2][3][2] = {{{0,0},{0,8},{1,0}}, {{0,0},{0,8},{1,8}}};
        for (int s = 0; s < 2; ++s) {
            const int bbase = (s == 0) ? BH_OFF : BX_OFF;
            for (int gi = 0; gi < 3; ++gi) {
                const float* W = WSET[s][gi];
                const int tile = TB[s][gi][0], nb = TB[s][gi][1];
                for (int dk = 0; dk < 2; ++dk) {
                    const int k = 2 * tid + dk;
                    const float* src = W + (size_t)k * H + F0;
                    const float4 a = *(const float4*)src;
                    const float4 bq = *(const float4*)(src + 4);
                    const float v[8] = {a.x, a.y, a.z, a.w, bq.x, bq.y, bq.z, bq.w};
#pragma unroll
                    for (int f = 0; f < 8; ++f)
                        *(unsigned short*)(smem + bbase + tile * 16384 +
                                           aswz(nb + f, k * 2)) = f2bf(v[f]);
                }
            }
        }
    }

    // ---- per-thread roles ----
    // staging: row srow (ring-local batch), 16 cols from scol
    const int srow = tid >> 5;
    const int scol = (tid & 31) * 16;
    // MFMA: wave w, lane: rc = A-row / B-col, kb = k-block
    const int w    = tid >> 6;
    const int lane = tid & 63;
    const int rc   = lane & 15;
    const int kb   = lane >> 4;
    int offk[4];
#pragma unroll
    for (int ks = 0; ks < 4; ++ks)
        offk[ks] = aswz(rc, (w * 4 + ks) * 64 + kb * 16);
    // epilogue: thread e<64 owns (batch em, feat ef)
    const int em = tid >> 3, ef = tid & 7;
    float bzv = 0.f, brv = 0.f, bhv = 0.f;
    if (tid < 64) {
        bzv = bz[F0 + ef]; brv = br[F0 + ef]; bhv = bh[F0 + ef];
    }

    // init h parity-0 with this block's own feature columns
    if (tid < 64) {
        const int idx = (g * 8 + em) * H + F0 + ef;
        __hip_atomic_store(&hgA[idx], h0[idx], __ATOMIC_RELAXED,
                           __HIP_MEMORY_SCOPE_AGENT);
    }

    // prefetch x(0)
    float4 xr[4];
    {
        const float* xp = x + ((size_t)(g * 8 + srow) * L + 0) * D + scol;
#pragma unroll
        for (int c = 0; c < 4; ++c) xr[c] = *(const float4*)(xp + 4 * c);
    }

    asm volatile("s_waitcnt vmcnt(0)" ::: "memory");
    __syncthreads();
    if (tid == 0)
        __hip_atomic_store(&flags[fc * 32], 1u, __ATOMIC_RELAXED,
                           __HIP_MEMORY_SCOPE_AGENT);

    for (int t = 0; t < L; ++t) {
        // ---- ring barrier: all 64 members' flags in {t+1, t+2} ----
        const unsigned stamp = (unsigned)(t + 1);
        if (tid < 64) {
            unsigned v;
            do {
                v = __hip_atomic_load(&flags[tid * 32], __ATOMIC_RELAXED,
                                      __HIP_MEMORY_SCOPE_AGENT);
                if (__all((v - stamp) <= 1u)) break;
                __builtin_amdgcn_s_sleep(1);
            } while (true);
        }
        __syncthreads();

        // ---- stage h(t) (coherent loads) and x(t) (regs) as bf16 hi/lo ----
        {
            const float* hsrc = ((t & 1) ? hgB : hgA) + (g * 8 + srow) * 512 + scol;
            const ull* hq = (const ull*)hsrc;
            float hv[16];
#pragma unroll
            for (int c = 0; c < 8; ++c) {
                const ull q = __hip_atomic_load(hq + c, __ATOMIC_RELAXED,
                                                __HIP_MEMORY_SCOPE_AGENT);
                hv[2 * c]     = __uint_as_float((unsigned)q);
                hv[2 * c + 1] = __uint_as_float((unsigned)(q >> 32));
            }
            float xv[16];
#pragma unroll
            for (int c = 0; c < 4; ++c) {
                xv[4 * c + 0] = xr[c].x; xv[4 * c + 1] = xr[c].y;
                xv[4 * c + 2] = xr[c].z; xv[4 * c + 3] = xr[c].w;
            }
#pragma unroll
            for (int gr = 0; gr < 2; ++gr) {
                uint4 phi, plo;
                const int ad = aswz(srow, scol * 2 + gr * 16);
                split8(hv + 8 * gr, phi, plo);
                *(uint4*)(smem + AH_HI + ad) = phi;
                *(uint4*)(smem + AH_LO + ad) = plo;
                split8(xv + 8 * gr, phi, plo);
                *(uint4*)(smem + AX_HI + ad) = phi;
                *(uint4*)(smem + AX_LO + ad) = plo;
            }
        }
        __syncthreads();

        // ---- MFMA: 4 passes (h_hi, h_lo, x_hi, x_lo) × 2 N-tiles,
        //      each wave covers K-range [w*128, w*128+128) ----
        f32x4 acc0 = {0.f, 0.f, 0.f, 0.f}, acc1 = {0.f, 0.f, 0.f, 0.f};
        {
            const char* Ab[4] = {smem + AH_HI, smem + AH_LO,
                                 smem + AX_HI, smem + AX_LO};
            const char* Bb[4] = {smem + BH_OFF, smem + BH_OFF,
                                 smem + BX_OFF, smem + BX_OFF};
#pragma unroll
            for (int p = 0; p < 4; ++p) {
#pragma unroll
                for (int ks = 0; ks < 4; ++ks) {
                    const short8v a  = *(const short8v*)(Ab[p] + offk[ks]);
                    const short8v b0 = *(const short8v*)(Bb[p] + offk[ks]);
                    const short8v b1 = *(const short8v*)(Bb[p] + 16384 + offk[ks]);
                    acc0 = __builtin_amdgcn_mfma_f32_16x16x32_bf16(a, b0, acc0, 0, 0, 0);
                    acc1 = __builtin_amdgcn_mfma_f32_16x16x32_bf16(a, b1, acc1, 0, 0, 0);
                }
            }
        }
        // write partial C (valid rows 0..7 live in lanes 0..31)
        if (lane < 32) {
            float* cbp = (float*)(smem + CB_OFF) + w * 272;
            const int mb = (lane >> 4) * 4, col = lane & 15;
#pragma unroll
            for (int reg = 0; reg < 4; ++reg) {
                cbp[(mb + reg) * 17 + col]       = acc0[reg];
                cbp[136 + (mb + reg) * 17 + col] = acc1[reg];
            }
        }
        __syncthreads();

        // ---- epilogue: 64 threads, one (batch, feature) each ----
        float hnv = 0.f;
        if (tid < 64) {
            float zz = 0.f, rr = 0.f, chh = 0.f, cxx = 0.f;
            const float* cb0 = (const float*)(smem + CB_OFF);
#pragma unroll
            for (int ww = 0; ww < 4; ++ww) {
                const float* cw = cb0 + ww * 272 + em * 17;
                zz  += cw[ef];        rr  += cw[8 + ef];
                chh += cw[136 + ef];  cxx += cw[136 + 8 + ef];
            }
            const int ad = aswz(em, (F0 + ef) * 2);
            const float hold = bf2f(*(const unsigned short*)(smem + AH_HI + ad))
                             + bf2f(*(const unsigned short*)(smem + AH_LO + ad));
            const float z = 1.f / (1.f + __expf(-(zz + bzv)));
            const float r = 1.f / (1.f + __expf(-(rr + brv)));
            const float pre = cxx + r * (chh + bhv);
            const float e = __expf(-2.f * fabsf(pre));
            float th = (1.f - e) / (1.f + e);
            th = (pre < 0.f) ? -th : th;
            hnv = z * hold + (1.f - z) * th;

            float* hdst = ((t + 1) & 1) ? hgB : hgA;
            __hip_atomic_store(&hdst[(g * 8 + em) * 512 + F0 + ef], hnv,
                               __ATOMIC_RELAXED, __HIP_MEMORY_SCOPE_AGENT);
        }

        // h stores acked, then arrive
        asm volatile("s_waitcnt vmcnt(0)" ::: "memory");
        __syncthreads();
        if (tid == 0)
            __hip_atomic_store(&flags[fc * 32], stamp + 1u, __ATOMIC_RELAXED,
                               __HIP_MEMORY_SCOPE_AGENT);

        // off the critical path: out writes + x prefetch for t+1
        if (tid < 64) {
            out[((size_t)(g * 8 + em) * L + t) * H + F0 + ef] = hnv;
            if (t == L - 1)
                out[(size_t)B * L * H + (size_t)(g * 8 + em) * H + F0 + ef] = hnv;
        }
        if (t + 1 < L) {
            const float* xp = x + ((size_t)(g * 8 + srow) * L + (t + 1)) * D + scol;
#pragma unroll
            for (int c = 0; c < 4; ++c) xr[c] = *(const float4*)(xp + 4 * c);
        }
    }
}

extern "C" void kernel_launch(void* const* d_in, const int* in_sizes, int n_in,
                              void* d_out, int out_size, void* d_ws, size_t ws_size,
                              hipStream_t stream) {
    const float* x   = (const float*)d_in[0];
    const float* h0  = (const float*)d_in[1];
    const float* Wxz = (const float*)d_in[2];
    const float* Whz = (const float*)d_in[3];
    const float* bz  = (const float*)d_in[4];
    const float* Wxr = (const float*)d_in[5];
    const float* Whr = (const float*)d_in[6];
    const float* br  = (const float*)d_in[7];
    const float* Wxh = (const float*)d_in[8];
    const float* Whh = (const float*)d_in[9];
    const float* bh  = (const float*)d_in[10];
    float* out = (float*)d_out;
    unsigned* ws = (unsigned*)d_ws;

    (void)hipFuncSetAttribute((const void*)gru_mfma,
                              hipFuncAttributeMaxDynamicSharedMemorySize,
                              (int)SMEM_BYTES);

    void* args[] = {(void*)&x, (void*)&h0, (void*)&Wxz, (void*)&Whz, (void*)&bz,
                    (void*)&Wxr, (void*)&Whr, (void*)&br, (void*)&Wxh, (void*)&Whh,
                    (void*)&bh, (void*)&out, (void*)&ws};
    hipError_t err = hipLaunchCooperativeKernel((void*)gru_mfma, dim3(256),
                                                dim3(256), args,
                                                (unsigned)SMEM_BYTES, stream);
    if (err != hipSuccess) {
        // kernel uses only its own flag barrier; 256 blocks at 1/CU are
        // trivially co-resident, so a plain launch is a safe fallback
        gru_mfma<<<dim3(256), dim3(256), SMEM_BYTES, stream>>>(
            x, h0, Wxz, Whz, bz, Wxr, Whr, br, Wxh, Whh, bh, out, ws);
    }
}